// Round 5
// baseline (469.950 us; speedup 1.0000x reference)
//
#include <hip/hip_runtime.h>

// ---------------- problem dims (fixed by reference) ----------------
// N=50000, E=640000, DIN=128, DH=256, DOUT=128

typedef float floatx4 __attribute__((ext_vector_type(4)));
typedef float floatx2 __attribute__((ext_vector_type(2)));
typedef short bf16x8 __attribute__((ext_vector_type(8)));

__device__ inline unsigned short f2bf(float f) {
    unsigned u = __float_as_uint(f);
    unsigned r = (u + 0x7fffu + ((u >> 16) & 1u)) >> 16;  // RNE
    return (unsigned short)r;
}
__device__ inline float bf2f_lo(unsigned v) { return __uint_as_float(v << 16); }
__device__ inline float bf2f_hi(unsigned v) { return __uint_as_float(v & 0xffff0000u); }

__device__ inline void gl_lds16(const void* g, void* l) {
    __builtin_amdgcn_global_load_lds((const __attribute__((address_space(1))) unsigned int*)g,
                                     (__attribute__((address_space(3))) unsigned int*)l,
                                     16, 0, 0);
}

// ================= CSR build =================
__global__ void hist_kernel(const int* __restrict__ dst, int* __restrict__ cnt, int E) {
    int i = blockIdx.x * blockDim.x + threadIdx.x;
    if (i < E) atomicAdd(&cnt[dst[i]], 1);
}

#define SCAN_CHUNK 2048

__global__ __launch_bounds__(256) void scan_blocksums(const int* __restrict__ cnt,
                                                      int* __restrict__ bsum, int N) {
    __shared__ int sh[256];
    int t = threadIdx.x;
    int base = blockIdx.x * SCAN_CHUNK + t * 8;
    int s = 0;
#pragma unroll
    for (int i = 0; i < 8; i++) {
        int idx = base + i;
        if (idx < N) s += cnt[idx];
    }
    sh[t] = s;
    __syncthreads();
    for (int off = 1; off < 256; off <<= 1) {
        int v = (t >= off) ? sh[t - off] : 0;
        __syncthreads();
        sh[t] += v;
        __syncthreads();
    }
    if (t == 255) bsum[blockIdx.x] = sh[255];
}

__global__ __launch_bounds__(256) void scan_bsums(const int* __restrict__ bsum,
                                                  int* __restrict__ boff, int NB,
                                                  int* __restrict__ rowptr, int N, int E) {
    __shared__ int sh[256];
    int t = threadIdx.x;
    int v = (t < NB) ? bsum[t] : 0;
    sh[t] = v;
    __syncthreads();
    for (int off = 1; off < 256; off <<= 1) {
        int u = (t >= off) ? sh[t - off] : 0;
        __syncthreads();
        sh[t] += u;
        __syncthreads();
    }
    if (t < NB) boff[t] = sh[t] - v;
    if (t == 0) rowptr[N] = E;
}

__global__ __launch_bounds__(256) void scan_final(const int* __restrict__ cnt,
                                                  const int* __restrict__ boff,
                                                  int* __restrict__ rowptr,
                                                  int* __restrict__ cursor,
                                                  float* __restrict__ invdeg, int N) {
    __shared__ int sh[256];
    int t = threadIdx.x;
    int base = blockIdx.x * SCAN_CHUNK + t * 8;
    int c[8];
    int s = 0;
#pragma unroll
    for (int i = 0; i < 8; i++) {
        int idx = base + i;
        c[i] = (idx < N) ? cnt[idx] : 0;
        s += c[i];
    }
    sh[t] = s;
    __syncthreads();
    for (int off = 1; off < 256; off <<= 1) {
        int v = (t >= off) ? sh[t - off] : 0;
        __syncthreads();
        sh[t] += v;
        __syncthreads();
    }
    int run = boff[blockIdx.x] + sh[t] - s;
#pragma unroll
    for (int i = 0; i < 8; i++) {
        int idx = base + i;
        if (idx < N) {
            rowptr[idx] = run;
            cursor[idx] = run;
            invdeg[idx] = 1.0f / (float)(c[i] > 1 ? c[i] : 1);
            run += c[i];
        }
    }
}

__global__ void scatter_kernel(const int* __restrict__ src, const int* __restrict__ dst,
                               int* __restrict__ cursor, int* __restrict__ col, int E) {
    int i = blockIdx.x * blockDim.x + threadIdx.x;
    if (i < E) {
        int p = atomicAdd(&cursor[dst[i]], 1);
        col[p] = src[i];
    }
}

// ================= fused weight prep =================
// WtC [512,256]: rows 0-255 = [W1l;W1r]^T (u), rows 256-511 = [0;Wsk]^T (s)
// Wt2 [256,512]  ;  Wt3 [256,256]: rows 0-127 W3l^T, 128-255 W3r^T
// biasC [512] = [b1l | bsk]
__global__ void prep_weights(const float* __restrict__ W1l, const float* __restrict__ W1r,
                             const float* __restrict__ Wsk, const float* __restrict__ W2l,
                             const float* __restrict__ W2r, const float* __restrict__ W3l,
                             const float* __restrict__ W3r, const float* __restrict__ b1l,
                             const float* __restrict__ bsk,
                             unsigned short* __restrict__ WtC, unsigned short* __restrict__ Wt2,
                             unsigned short* __restrict__ Wt3, float* __restrict__ biasC) {
    int i = blockIdx.x * blockDim.x + threadIdx.x;
    if (i < 32768) {                        // W1l [128,256]
        int k = i >> 8, n = i & 255;
        WtC[n * 256 + k] = f2bf(W1l[i]);
    } else if (i < 65536) {                 // W1r
        int j = i - 32768, k = j >> 8, n = j & 255;
        WtC[n * 256 + 128 + k] = f2bf(W1r[j]);
    } else if (i < 98304) {                 // Wsk -> rows 256-511, k-half 128-255
        int j = i - 65536, k = j >> 8, n = j & 255;
        WtC[(256 + n) * 256 + 128 + k] = f2bf(Wsk[j]);
    } else if (i < 131072) {                // zero-fill rows 256-511, k-half 0-127
        int j = i - 98304, k = j >> 8, n = j & 255;
        WtC[(256 + n) * 256 + k] = 0;
    } else if (i < 196608) {                // W2l [256,256]
        int j = i - 131072, k = j >> 8, n = j & 255;
        Wt2[n * 512 + k] = f2bf(W2l[j]);
    } else if (i < 262144) {                // W2r
        int j = i - 196608, k = j >> 8, n = j & 255;
        Wt2[n * 512 + 256 + k] = f2bf(W2r[j]);
    } else if (i < 294912) {                // W3l [256,128]
        int j = i - 262144, k = j >> 7, n = j & 127;
        Wt3[n * 256 + k] = f2bf(W3l[j]);
    } else if (i < 327680) {                // W3r
        int j = i - 294912, k = j >> 7, n = j & 127;
        Wt3[(128 + n) * 256 + k] = f2bf(W3r[j]);
    } else if (i < 328192) {                // biasC [512]
        int j = i - 327680;
        biasC[j] = (j < 256) ? b1l[j] : bsk[j - 256];
    }
}

// x fp32 [N,128] -> bf16 into A1cat right half (stride 256) + fp8 shadow X8 [N,128]
__global__ void cvt_x2(const float* __restrict__ x, unsigned short* __restrict__ A1cat,
                       unsigned char* __restrict__ X8, int total32) {
    int i = blockIdx.x * blockDim.x + threadIdx.x;
    if (i >= total32) return;
    int r = i >> 5, c4 = (i & 31) * 4;
    float4 v = *(const float4*)(x + (size_t)r * 128 + c4);
    ushort4 o;
    o.x = f2bf(v.x); o.y = f2bf(v.y); o.z = f2bf(v.z); o.w = f2bf(v.w);
    *(ushort4*)(A1cat + (size_t)r * 256 + 128 + c4) = o;
    unsigned wpk = 0;
    wpk = __builtin_amdgcn_cvt_pk_fp8_f32(v.x, v.y, wpk, false);
    wpk = __builtin_amdgcn_cvt_pk_fp8_f32(v.z, v.w, wpk, true);
    *(unsigned*)(X8 + (size_t)r * 128 + c4) = wpk;
}

// ================= fp8 helpers =================
__device__ inline void accum_fp8(uint2 v, float m, float* a) {
    floatx2 p;
    p = __builtin_amdgcn_cvt_pk_f32_fp8(v.x, false); a[0] = fmaf(m, p.x, a[0]); a[1] = fmaf(m, p.y, a[1]);
    p = __builtin_amdgcn_cvt_pk_f32_fp8(v.x, true);  a[2] = fmaf(m, p.x, a[2]); a[3] = fmaf(m, p.y, a[3]);
    p = __builtin_amdgcn_cvt_pk_f32_fp8(v.y, false); a[4] = fmaf(m, p.x, a[4]); a[5] = fmaf(m, p.y, a[5]);
    p = __builtin_amdgcn_cvt_pk_f32_fp8(v.y, true);  a[6] = fmaf(m, p.x, a[6]); a[7] = fmaf(m, p.y, a[7]);
}

// ====== column-chunked fp8 gather-mean: blockIdx.y = 64B column slice of the table ======
// One wave per node per slice. 8 lanes (sub) cover the 64B slice; 8 groups (g) process
// 8 edges per round, x4 predicated unroll = 32 gathers in flight. The 64B slice working
// set (<=3.2 MB) stays L2-resident during its dispatch phase (linear block order).
// RSB = table row stride in bytes (128 for X8, 256 for H8).
template <int RSB>
__global__ __launch_bounds__(256) void agg_fp8_c(const int* __restrict__ rowptr,
                                                 const int* __restrict__ col,
                                                 const float* __restrict__ invdeg,
                                                 const unsigned char* __restrict__ T8,
                                                 unsigned short* __restrict__ out, int ostride, int N) {
    int wid = (blockIdx.x * blockDim.x + threadIdx.x) >> 6;
    int lane = threadIdx.x & 63;
    if (wid >= N) return;
    int co = blockIdx.y * 64;    // byte (== fp8-column) offset of this slice
    int sub = lane & 7;          // 8B slot within slice
    int g = lane >> 3;           // edge group 0..7
    const unsigned char* To = T8 + co + sub * 8;
    int s = rowptr[wid], e = rowptr[wid + 1];
    float a[8] = {0.f, 0.f, 0.f, 0.f, 0.f, 0.f, 0.f, 0.f};
    for (int j = s + g; j < e; j += 32) {
        int j1 = (j + 8 < e) ? j + 8 : j;
        int j2 = (j + 16 < e) ? j + 16 : j;
        int j3 = (j + 24 < e) ? j + 24 : j;
        float m1 = (j + 8 < e) ? 1.f : 0.f;
        float m2 = (j + 16 < e) ? 1.f : 0.f;
        float m3 = (j + 24 < e) ? 1.f : 0.f;
        int c0 = col[j], c1 = col[j1], c2 = col[j2], c3 = col[j3];
        uint2 v0 = *(const uint2*)(To + (size_t)c0 * RSB);
        uint2 v1 = *(const uint2*)(To + (size_t)c1 * RSB);
        uint2 v2 = *(const uint2*)(To + (size_t)c2 * RSB);
        uint2 v3 = *(const uint2*)(To + (size_t)c3 * RSB);
        accum_fp8(v0, 1.f, a);
        accum_fp8(v1, m1, a);
        accum_fp8(v2, m2, a);
        accum_fp8(v3, m3, a);
    }
#pragma unroll
    for (int i = 0; i < 8; i++) {
        a[i] += __shfl_xor(a[i], 8, 64);
        a[i] += __shfl_xor(a[i], 16, 64);
        a[i] += __shfl_xor(a[i], 32, 64);
    }
    if (g == 0) {
        float inv = invdeg[wid];
        uint4 o;
        o.x = (unsigned)f2bf(a[0] * inv) | ((unsigned)f2bf(a[1] * inv) << 16);
        o.y = (unsigned)f2bf(a[2] * inv) | ((unsigned)f2bf(a[3] * inv) << 16);
        o.z = (unsigned)f2bf(a[4] * inv) | ((unsigned)f2bf(a[5] * inv) << 16);
        o.w = (unsigned)f2bf(a[6] * inv) | ((unsigned)f2bf(a[7] * inv) << 16);
        *(uint4*)(out + (size_t)wid * ostride + co + sub * 8) = o;
    }
}

// chunked final gather: T bf16 [N,128] (256B rows), slice = 32 bf16 cols (64B).
// out = mean-agg(T) + R (fp32), per slice.
__global__ __launch_bounds__(256) void agg_fin_c(const int* __restrict__ rowptr,
                                                 const int* __restrict__ col,
                                                 const float* __restrict__ invdeg,
                                                 const unsigned short* __restrict__ T,
                                                 const float* __restrict__ R,
                                                 float* __restrict__ out, int N) {
    int wid = (blockIdx.x * blockDim.x + threadIdx.x) >> 6;
    int lane = threadIdx.x & 63;
    if (wid >= N) return;
    int co2 = blockIdx.y * 32;   // bf16-column offset of this slice
    int sub = lane & 7;          // 4-col slot
    int g = lane >> 3;           // edge group 0..7
    const unsigned short* To = T + co2 + sub * 4;
    int s = rowptr[wid], e = rowptr[wid + 1];
    float a0 = 0.f, a1 = 0.f, a2 = 0.f, a3 = 0.f;
    for (int j = s + g; j < e; j += 32) {
        int j1 = (j + 8 < e) ? j + 8 : j;
        int j2 = (j + 16 < e) ? j + 16 : j;
        int j3 = (j + 24 < e) ? j + 24 : j;
        float m1 = (j + 8 < e) ? 1.f : 0.f;
        float m2 = (j + 16 < e) ? 1.f : 0.f;
        float m3 = (j + 24 < e) ? 1.f : 0.f;
        int c0 = col[j], c1 = col[j1], c2 = col[j2], c3 = col[j3];
        uint2 v0 = *(const uint2*)(To + (size_t)c0 * 128);
        uint2 v1 = *(const uint2*)(To + (size_t)c1 * 128);
        uint2 v2 = *(const uint2*)(To + (size_t)c2 * 128);
        uint2 v3 = *(const uint2*)(To + (size_t)c3 * 128);
        a0 += bf2f_lo(v0.x); a1 += bf2f_hi(v0.x); a2 += bf2f_lo(v0.y); a3 += bf2f_hi(v0.y);
        a0 = fmaf(m1, bf2f_lo(v1.x), a0); a1 = fmaf(m1, bf2f_hi(v1.x), a1);
        a2 = fmaf(m1, bf2f_lo(v1.y), a2); a3 = fmaf(m1, bf2f_hi(v1.y), a3);
        a0 = fmaf(m2, bf2f_lo(v2.x), a0); a1 = fmaf(m2, bf2f_hi(v2.x), a1);
        a2 = fmaf(m2, bf2f_lo(v2.y), a2); a3 = fmaf(m2, bf2f_hi(v2.y), a3);
        a0 = fmaf(m3, bf2f_lo(v3.x), a0); a1 = fmaf(m3, bf2f_hi(v3.x), a1);
        a2 = fmaf(m3, bf2f_lo(v3.y), a2); a3 = fmaf(m3, bf2f_hi(v3.y), a3);
    }
#pragma unroll
    for (int off = 8; off < 64; off <<= 1) {
        a0 += __shfl_xor(a0, off, 64);
        a1 += __shfl_xor(a1, off, 64);
        a2 += __shfl_xor(a2, off, 64);
        a3 += __shfl_xor(a3, off, 64);
    }
    if (g == 0) {
        float inv = invdeg[wid];
        float4 r = *(const float4*)(R + (size_t)wid * 128 + co2 + sub * 4);
        float4 o;
        o.x = a0 * inv + r.x;
        o.y = a1 * inv + r.y;
        o.z = a2 * inv + r.z;
        o.w = a3 * inv + r.w;
        *(float4*)(out + (size_t)wid * 128 + co2 + sub * 4) = o;
    }
}

// ====== GEMM (round-3 structure): A via LDS dbuf, B direct global->VGPR (L2-resident
// weights), fused LN/ReLU/residual epilogue through an LDS row-exchange buffer. ======
// 512 threads = 8 waves; block computes 128 rows x COLS (COLS = NPAN*256).
// MODE 0 (layer1): COLS=512 = [u|s]; h = relu(LN(u+b1l)*g+b) + (s+bsk) -> bf16 + fp8.
// MODE 1 (layer2): COLS=256; h2 = relu(LN(u2+b2l)*g+b) + resid(bf16 stride 512) -> bf16.
// MODE 2 (layer3): COLS=256; cols 0-127 -> t3 bf16 (no bias); cols 128-255 + bias -> r3 fp32.
template <int KIT, int NPAN, int MODE>
__global__ __launch_bounds__(512) void gemm_fused(
    const unsigned short* __restrict__ A, int lda,
    const unsigned short* __restrict__ B, int ldb,
    const float* __restrict__ bias,
    const float* __restrict__ gamma, const float* __restrict__ beta,
    const unsigned short* __restrict__ resid,
    unsigned short* __restrict__ outb,
    unsigned char* __restrict__ h8,
    float* __restrict__ outf, int M) {
    constexpr int COLS = NPAN * 256;
    constexpr int LNW = COLS + 8;              // exchange-buffer row stride (floats)
    constexpr int STAGE_E = 128 * 64;          // A-tile bf16 elems (16 KB)
    constexpr int STAGE_F = 2 * STAGE_E / 2;   // dbuf bytes/4 = floats (8192)
    constexpr int SMEM_F = (STAGE_F > 32 * LNW) ? STAGE_F : 32 * LNW;
    __shared__ __align__(16) float smemf[SMEM_F];
    unsigned short* sbase = (unsigned short*)smemf;

    int t = threadIdx.x;
    int lane = t & 63, w = t >> 6;
    int bm = blockIdx.x * 128;
    int wm = (w & 1) * 64, wn = (w >> 1) * 64;
    int m16 = lane & 15, kq = lane >> 4;

    floatx4 acc[NPAN][4][4];
#pragma unroll
    for (int p = 0; p < NPAN; p++)
#pragma unroll
        for (int i = 0; i < 4; i++)
#pragma unroll
            for (int j = 0; j < 4; j++) acc[p][i][j] = (floatx4){0.f, 0.f, 0.f, 0.f};

    const int s_row0 = t >> 3;                 // staging rows 0..63 (i=0), +64 (i=1)
    const int s_j = t & 7;

    auto stage = [&](int kt, int bsel) {
        unsigned short* s = sbase + bsel * STAGE_E;
        int k0 = kt * 64;
#pragma unroll
        for (int i = 0; i < 2; i++) {
            int row = s_row0 + i * 64;
            int kc = s_j ^ (row & 7);          // XOR-swizzled source k-chunk
            int rowA = bm + row;
            if (rowA > M - 1) rowA = M - 1;
            gl_lds16(A + (size_t)rowA * lda + k0 + kc * 8, (void*)&s[(size_t)(i * 512 + t) * 8]);
        }
    };

    stage(0, 0);
    __syncthreads();
    for (int kt = 0; kt < KIT; kt++) {
        if (kt + 1 < KIT) stage(kt + 1, (kt & 1) ^ 1);
        const unsigned short* sA = sbase + (kt & 1) * STAGE_E;
#pragma unroll
        for (int ks = 0; ks < 2; ks++) {
            int kcl = (ks << 2) | kq;
            bf16x8 af[4];
#pragma unroll
            for (int mi = 0; mi < 4; mi++)
                af[mi] = *(const bf16x8*)&sA[(wm + mi * 16 + m16) * 64 + (kcl ^ (m16 & 7)) * 8];
#pragma unroll
            for (int p = 0; p < NPAN; p++) {
                if (MODE == 0 && p == 1 && kt * 64 < 128) continue;  // Wsk panel: k<128 is zero
                const unsigned short* Bp = B + (size_t)(wn + p * 256) * ldb + kt * 64;
                bf16x8 bf[4];
#pragma unroll
                for (int ni = 0; ni < 4; ni++)
                    bf[ni] = *(const bf16x8*)&Bp[(size_t)(ni * 16 + m16) * ldb + kcl * 8];
#pragma unroll
                for (int mi = 0; mi < 4; mi++)
#pragma unroll
                    for (int ni = 0; ni < 4; ni++)
                        acc[p][mi][ni] =
                            __builtin_amdgcn_mfma_f32_16x16x32_bf16(af[mi], bf[ni], acc[p][mi][ni], 0, 0, 0);
            }
        }
        __syncthreads();
    }

    // ---- fused epilogue: 4 rounds of 32 rows through LDS exchange buffer ----
    float* lnb = smemf;
    int c4 = lane * 4;
    float4 bu = {0.f, 0.f, 0.f, 0.f}, bs = {0.f, 0.f, 0.f, 0.f};
    float4 gv = {0.f, 0.f, 0.f, 0.f}, bv = {0.f, 0.f, 0.f, 0.f};
    float4 b3 = {0.f, 0.f, 0.f, 0.f};
    if (MODE == 0) {
        bu = *(const float4*)&bias[c4];
        bs = *(const float4*)&bias[256 + c4];
        gv = *(const float4*)&gamma[c4];
        bv = *(const float4*)&beta[c4];
    } else if (MODE == 1) {
        bu = *(const float4*)&bias[c4];
        gv = *(const float4*)&gamma[c4];
        bv = *(const float4*)&beta[c4];
    } else {
        if (lane >= 32) b3 = *(const float4*)&bias[c4 - 128];
    }

#pragma unroll
    for (int g4 = 0; g4 < 4; g4++) {
        if (wm == (g4 >> 1) * 64) {            // this wave owns rows g4*32..+32
            int mi0 = (g4 & 1) * 2;
#pragma unroll
            for (int p = 0; p < NPAN; p++)
#pragma unroll
                for (int mm = 0; mm < 2; mm++)
#pragma unroll
                    for (int ni = 0; ni < 4; ni++)
#pragma unroll
                        for (int r = 0; r < 4; r++)
                            lnb[(mm * 16 + kq * 4 + r) * LNW + wn + p * 256 + ni * 16 + m16] =
                                acc[p][mi0 + mm][ni][r];
        }
        __syncthreads();
#pragma unroll
        for (int rr = 0; rr < 4; rr++) {
            int lrow = w * 4 + rr;             // 8 waves x 4 rows = 32
            int grow = bm + g4 * 32 + lrow;
            bool valid = grow < M;
            float4 u = *(const float4*)&lnb[lrow * LNW + c4];
            if (MODE <= 1) {
                u.x += bu.x; u.y += bu.y; u.z += bu.z; u.w += bu.w;
                float s1 = (u.x + u.y) + (u.z + u.w);
                float s2 = (u.x * u.x + u.y * u.y) + (u.z * u.z + u.w * u.w);
#pragma unroll
                for (int off = 1; off < 64; off <<= 1) {
                    s1 += __shfl_xor(s1, off, 64);
                    s2 += __shfl_xor(s2, off, 64);
                }
                float mu = s1 * (1.f / 256.f);
                float var = s2 * (1.f / 256.f) - mu * mu;
                float rs = rsqrtf(var + 1e-5f);
                float a0, a1, a2, a3;
                if (MODE == 0) {
                    float4 sv = *(const float4*)&lnb[lrow * LNW + 256 + c4];
                    a0 = sv.x + bs.x; a1 = sv.y + bs.y; a2 = sv.z + bs.z; a3 = sv.w + bs.w;
                } else {
                    int gr = valid ? grow : M - 1;
                    uint2 hv = *(const uint2*)(resid + (size_t)gr * 512 + c4);
                    a0 = bf2f_lo(hv.x); a1 = bf2f_hi(hv.x); a2 = bf2f_lo(hv.y); a3 = bf2f_hi(hv.y);
                }
                float o0 = fmaxf((u.x - mu) * rs * gv.x + bv.x, 0.f) + a0;
                float o1 = fmaxf((u.y - mu) * rs * gv.y + bv.y, 0.f) + a1;
                float o2 = fmaxf((u.z - mu) * rs * gv.z + bv.z, 0.f) + a2;
                float o3 = fmaxf((u.w - mu) * rs * gv.w + bv.w, 0.f) + a3;
                if (valid) {
                    ushort4 o;
                    o.x = f2bf(o0); o.y = f2bf(o1); o.z = f2bf(o2); o.w = f2bf(o3);
                    *(ushort4*)(outb + (size_t)grow * 512 + c4) = o;
                    if (MODE == 0) {
                        unsigned wpk = 0;
                        wpk = __builtin_amdgcn_cvt_pk_fp8_f32(o0, o1, wpk, false);
                        wpk = __builtin_amdgcn_cvt_pk_fp8_f32(o2, o3, wpk, true);
                        *(unsigned*)(h8 + (size_t)grow * 256 + c4) = wpk;
                    }
                }
            } else {
                if (valid) {
                    if (lane < 32) {
                        ushort4 o;
                        o.x = f2bf(u.x); o.y = f2bf(u.y); o.z = f2bf(u.z); o.w = f2bf(u.w);
                        *(ushort4*)(outb + (size_t)grow * 128 + c4) = o;
                    } else {
                        float4 o;
                        o.x = u.x + b3.x; o.y = u.y + b3.y; o.z = u.z + b3.z; o.w = u.w + b3.w;
                        *(float4*)(outf + (size_t)grow * 128 + (c4 - 128)) = o;
                    }
                }
            }
        }
        __syncthreads();
    }
}

// ================= launch =================
extern "C" void kernel_launch(void* const* d_in, const int* in_sizes, int n_in,
                              void* d_out, int out_size, void* d_ws, size_t ws_size,
                              hipStream_t stream) {
    const float* x   = (const float*)d_in[0];
    const int*   ei  = (const int*)d_in[1];
    const float* W1l = (const float*)d_in[2];
    const float* b1l = (const float*)d_in[3];
    const float* W1r = (const float*)d_in[4];
    const float* g1  = (const float*)d_in[5];
    const float* be1 = (const float*)d_in[6];
    const float* Wsk = (const float*)d_in[7];
    const float* bsk = (const float*)d_in[8];
    const float* W2l = (const float*)d_in[9];
    const float* b2l = (const float*)d_in[10];
    const float* W2r = (const float*)d_in[11];
    const float* g2  = (const float*)d_in[12];
    const float* be2 = (const float*)d_in[13];
    const float* W3l = (const float*)d_in[14];
    const float* b3l = (const float*)d_in[15];
    const float* W3r = (const float*)d_in[16];

    const int N = in_sizes[0] / 128;
    const int E = in_sizes[1] / 2;
    const int* src = ei;
    const int* dst = ei + E;

    char* p = (char*)d_ws;
    auto alloc = [&](size_t bytes) {
        void* r = (void*)p;
        p += (bytes + 255) & ~(size_t)255;
        return r;
    };
    int*   cnt    = (int*)alloc(sizeof(int) * N);
    int*   rowptr = (int*)alloc(sizeof(int) * (N + 1));
    int*   cursor = (int*)alloc(sizeof(int) * N);
    float* invdeg = (float*)alloc(sizeof(float) * N);
    int*   col    = (int*)alloc(sizeof(int) * E);
    int*   bsum   = (int*)alloc(sizeof(int) * 256);
    int*   boff   = (int*)alloc(sizeof(int) * 256);
    unsigned short* A1cat = (unsigned short*)alloc(sizeof(short) * (size_t)N * 256);  // [agg1|x]; later t3
    unsigned short* A2cat = (unsigned short*)alloc(sizeof(short) * (size_t)N * 512);  // [agg2|h] -> [h2|h]
    float* r3 = (float*)alloc(sizeof(float) * (size_t)N * 128);
    unsigned char* H8 = (unsigned char*)alloc((size_t)N * 256);                       // fp8 h shadow
    unsigned char* X8 = (unsigned char*)alloc((size_t)N * 128);                       // fp8 x shadow
    unsigned short* WtC = (unsigned short*)alloc(sizeof(short) * 512 * 256);
    unsigned short* Wt2 = (unsigned short*)alloc(sizeof(short) * 256 * 512);
    unsigned short* Wt3 = (unsigned short*)alloc(sizeof(short) * 256 * 256);
    float* biasC = (float*)alloc(sizeof(float) * 512);
    unsigned short* t3 = A1cat;

    // ---- CSR build ----
    hipMemsetAsync(cnt, 0, sizeof(int) * N, stream);
    hist_kernel<<<(E + 255) / 256, 256, 0, stream>>>(dst, cnt, E);
    int NB = (N + SCAN_CHUNK - 1) / SCAN_CHUNK;
    scan_blocksums<<<NB, 256, 0, stream>>>(cnt, bsum, N);
    scan_bsums<<<1, 256, 0, stream>>>(bsum, boff, NB, rowptr, N, E);
    scan_final<<<NB, 256, 0, stream>>>(cnt, boff, rowptr, cursor, invdeg, N);
    scatter_kernel<<<(E + 255) / 256, 256, 0, stream>>>(src, dst, cursor, col, E);

    // ---- prep ----
    prep_weights<<<(328192 + 255) / 256, 256, 0, stream>>>(W1l, W1r, Wsk, W2l, W2r, W3l, W3r,
                                                           b1l, bsk, WtC, Wt2, Wt3, biasC);
    cvt_x2<<<((N * 32) + 255) / 256, 256, 0, stream>>>(x, A1cat, X8, N * 32);

    int aggBlocks = (N + 3) / 4;
    int mBlocks = (N + 127) / 128;

    // ---- layer 1: chunked agg (2 x 64B slices) -> fused GEMM+LN+ReLU+skip ----
    agg_fp8_c<128><<<dim3(aggBlocks, 2), 256, 0, stream>>>(rowptr, col, invdeg, X8, A1cat, 256, N);
    gemm_fused<4, 2, 0><<<mBlocks, 512, 0, stream>>>(A1cat, 256, WtC, 256, biasC, g1, be1,
                                                     nullptr, A2cat + 256, H8, nullptr, N);

    // ---- layer 2: chunked agg (4 x 64B slices) -> fused GEMM+LN+ReLU+residual ----
    agg_fp8_c<256><<<dim3(aggBlocks, 4), 256, 0, stream>>>(rowptr, col, invdeg, H8, A2cat, 512, N);
    gemm_fused<8, 1, 1><<<mBlocks, 512, 0, stream>>>(A2cat, 512, Wt2, 512, b2l, g2, be2,
                                                     A2cat + 256, A2cat, nullptr, nullptr, N);

    // ---- layer 3: split GEMM (t3 bf16 | r3 fp32+bias) -> chunked final agg (4 slices) ----
    gemm_fused<4, 1, 2><<<mBlocks, 512, 0, stream>>>(A2cat, 512, Wt3, 256, b3l, nullptr, nullptr,
                                                     nullptr, t3, nullptr, r3, N);
    agg_fin_c<<<dim3(aggBlocks, 4), 256, 0, stream>>>(rowptr, col, invdeg, t3, r3, (float*)d_out, N);
}

// Round 6
// 376.898 us; speedup vs baseline: 1.2469x; 1.2469x over previous
//
#include <hip/hip_runtime.h>

// ---------------- problem dims (fixed by reference) ----------------
// N=50000, E=640000, DIN=128, DH=256, DOUT=128

typedef float floatx4 __attribute__((ext_vector_type(4)));
typedef float floatx2 __attribute__((ext_vector_type(2)));
typedef short bf16x8 __attribute__((ext_vector_type(8)));

__device__ inline unsigned short f2bf(float f) {
    unsigned u = __float_as_uint(f);
    unsigned r = (u + 0x7fffu + ((u >> 16) & 1u)) >> 16;  // RNE
    return (unsigned short)r;
}
__device__ inline float bf2f_lo(unsigned v) { return __uint_as_float(v << 16); }
__device__ inline float bf2f_hi(unsigned v) { return __uint_as_float(v & 0xffff0000u); }

__device__ inline void gl_lds16(const void* g, void* l) {
    __builtin_amdgcn_global_load_lds((const __attribute__((address_space(1))) unsigned int*)g,
                                     (__attribute__((address_space(3))) unsigned int*)l,
                                     16, 0, 0);
}

// ================= CSR build =================
__global__ void hist_kernel(const int* __restrict__ dst, int* __restrict__ cnt, int E) {
    int i = blockIdx.x * blockDim.x + threadIdx.x;
    if (i < E) atomicAdd(&cnt[dst[i]], 1);
}

#define SCAN_CHUNK 2048

__global__ __launch_bounds__(256) void scan_blocksums(const int* __restrict__ cnt,
                                                      int* __restrict__ bsum, int N) {
    __shared__ int sh[256];
    int t = threadIdx.x;
    int base = blockIdx.x * SCAN_CHUNK + t * 8;
    int s = 0;
#pragma unroll
    for (int i = 0; i < 8; i++) {
        int idx = base + i;
        if (idx < N) s += cnt[idx];
    }
    sh[t] = s;
    __syncthreads();
    for (int off = 1; off < 256; off <<= 1) {
        int v = (t >= off) ? sh[t - off] : 0;
        __syncthreads();
        sh[t] += v;
        __syncthreads();
    }
    if (t == 255) bsum[blockIdx.x] = sh[255];
}

__global__ __launch_bounds__(256) void scan_bsums(const int* __restrict__ bsum,
                                                  int* __restrict__ boff, int NB,
                                                  int* __restrict__ rowptr, int N, int E) {
    __shared__ int sh[256];
    int t = threadIdx.x;
    int v = (t < NB) ? bsum[t] : 0;
    sh[t] = v;
    __syncthreads();
    for (int off = 1; off < 256; off <<= 1) {
        int u = (t >= off) ? sh[t - off] : 0;
        __syncthreads();
        sh[t] += u;
        __syncthreads();
    }
    if (t < NB) boff[t] = sh[t] - v;
    if (t == 0) rowptr[N] = E;
}

__global__ __launch_bounds__(256) void scan_final(const int* __restrict__ cnt,
                                                  const int* __restrict__ boff,
                                                  int* __restrict__ rowptr,
                                                  int* __restrict__ cursor,
                                                  float* __restrict__ invdeg, int N) {
    __shared__ int sh[256];
    int t = threadIdx.x;
    int base = blockIdx.x * SCAN_CHUNK + t * 8;
    int c[8];
    int s = 0;
#pragma unroll
    for (int i = 0; i < 8; i++) {
        int idx = base + i;
        c[i] = (idx < N) ? cnt[idx] : 0;
        s += c[i];
    }
    sh[t] = s;
    __syncthreads();
    for (int off = 1; off < 256; off <<= 1) {
        int v = (t >= off) ? sh[t - off] : 0;
        __syncthreads();
        sh[t] += v;
        __syncthreads();
    }
    int run = boff[blockIdx.x] + sh[t] - s;
#pragma unroll
    for (int i = 0; i < 8; i++) {
        int idx = base + i;
        if (idx < N) {
            rowptr[idx] = run;
            cursor[idx] = run;
            invdeg[idx] = 1.0f / (float)(c[i] > 1 ? c[i] : 1);
            run += c[i];
        }
    }
}

__global__ void scatter_kernel(const int* __restrict__ src, const int* __restrict__ dst,
                               int* __restrict__ cursor, int* __restrict__ col, int E) {
    int i = blockIdx.x * blockDim.x + threadIdx.x;
    if (i < E) {
        int p = atomicAdd(&cursor[dst[i]], 1);
        col[p] = src[i];
    }
}

// ================= fused weight prep =================
// WtC [512,256]: rows 0-255 = [W1l;W1r]^T (u), rows 256-511 = [0;Wsk]^T (s)
// Wt2 [256,512]  ;  Wt3 [256,256]: rows 0-127 W3l^T, 128-255 W3r^T
// biasC [512] = [b1l | bsk]
__global__ void prep_weights(const float* __restrict__ W1l, const float* __restrict__ W1r,
                             const float* __restrict__ Wsk, const float* __restrict__ W2l,
                             const float* __restrict__ W2r, const float* __restrict__ W3l,
                             const float* __restrict__ W3r, const float* __restrict__ b1l,
                             const float* __restrict__ bsk,
                             unsigned short* __restrict__ WtC, unsigned short* __restrict__ Wt2,
                             unsigned short* __restrict__ Wt3, float* __restrict__ biasC) {
    int i = blockIdx.x * blockDim.x + threadIdx.x;
    if (i < 32768) {                        // W1l [128,256]
        int k = i >> 8, n = i & 255;
        WtC[n * 256 + k] = f2bf(W1l[i]);
    } else if (i < 65536) {                 // W1r
        int j = i - 32768, k = j >> 8, n = j & 255;
        WtC[n * 256 + 128 + k] = f2bf(W1r[j]);
    } else if (i < 98304) {                 // Wsk -> rows 256-511, k-half 128-255
        int j = i - 65536, k = j >> 8, n = j & 255;
        WtC[(256 + n) * 256 + 128 + k] = f2bf(Wsk[j]);
    } else if (i < 131072) {                // zero-fill rows 256-511, k-half 0-127
        int j = i - 98304, k = j >> 8, n = j & 255;
        WtC[(256 + n) * 256 + k] = 0;
    } else if (i < 196608) {                // W2l [256,256]
        int j = i - 131072, k = j >> 8, n = j & 255;
        Wt2[n * 512 + k] = f2bf(W2l[j]);
    } else if (i < 262144) {                // W2r
        int j = i - 196608, k = j >> 8, n = j & 255;
        Wt2[n * 512 + 256 + k] = f2bf(W2r[j]);
    } else if (i < 294912) {                // W3l [256,128]
        int j = i - 262144, k = j >> 7, n = j & 127;
        Wt3[n * 256 + k] = f2bf(W3l[j]);
    } else if (i < 327680) {                // W3r
        int j = i - 294912, k = j >> 7, n = j & 127;
        Wt3[(128 + n) * 256 + k] = f2bf(W3r[j]);
    } else if (i < 328192) {                // biasC [512]
        int j = i - 327680;
        biasC[j] = (j < 256) ? b1l[j] : bsk[j - 256];
    }
}

// x fp32 [N,128] -> bf16 into A1cat right half (stride 256) + fp8 shadow X8 [N,128]
__global__ void cvt_x2(const float* __restrict__ x, unsigned short* __restrict__ A1cat,
                       unsigned char* __restrict__ X8, int total32) {
    int i = blockIdx.x * blockDim.x + threadIdx.x;
    if (i >= total32) return;
    int r = i >> 5, c4 = (i & 31) * 4;
    float4 v = *(const float4*)(x + (size_t)r * 128 + c4);
    ushort4 o;
    o.x = f2bf(v.x); o.y = f2bf(v.y); o.z = f2bf(v.z); o.w = f2bf(v.w);
    *(ushort4*)(A1cat + (size_t)r * 256 + 128 + c4) = o;
    unsigned wpk = 0;
    wpk = __builtin_amdgcn_cvt_pk_fp8_f32(v.x, v.y, wpk, false);
    wpk = __builtin_amdgcn_cvt_pk_fp8_f32(v.z, v.w, wpk, true);
    *(unsigned*)(X8 + (size_t)r * 128 + c4) = wpk;
}

// ================= group-per-node gather-mean kernels =================
// 16 fp8 -> 8 floatx2 accumulate (packed f32 fma)
__device__ inline void acc16_fp8(uint4 v, float m, floatx2* a) {
    floatx2 mm = {m, m};
    floatx2 p;
    p = __builtin_amdgcn_cvt_pk_f32_fp8(v.x, false); a[0] = p * mm + a[0];
    p = __builtin_amdgcn_cvt_pk_f32_fp8(v.x, true);  a[1] = p * mm + a[1];
    p = __builtin_amdgcn_cvt_pk_f32_fp8(v.y, false); a[2] = p * mm + a[2];
    p = __builtin_amdgcn_cvt_pk_f32_fp8(v.y, true);  a[3] = p * mm + a[3];
    p = __builtin_amdgcn_cvt_pk_f32_fp8(v.z, false); a[4] = p * mm + a[4];
    p = __builtin_amdgcn_cvt_pk_f32_fp8(v.z, true);  a[5] = p * mm + a[5];
    p = __builtin_amdgcn_cvt_pk_f32_fp8(v.w, false); a[6] = p * mm + a[6];
    p = __builtin_amdgcn_cvt_pk_f32_fp8(v.w, true);  a[7] = p * mm + a[7];
}

// fp8 gather-mean, group-per-node: LPR = RSB/16 lanes cover a full row (16B/lane);
// 64/LPR nodes per wave, no cross-lane reduction, no masked epilogue.
// Output bf16 (16 cols/lane) into out[node*ostride + sub*16 ..].
template <int RSB>
__global__ __launch_bounds__(256) void agg_fp8_g(const int* __restrict__ rowptr,
                                                 const int* __restrict__ col,
                                                 const float* __restrict__ invdeg,
                                                 const unsigned char* __restrict__ T8,
                                                 unsigned short* __restrict__ out, int ostride, int N) {
    constexpr int LPR = RSB / 16;   // 8 (layer1) or 16 (layer2)
    constexpr int NPW = 64 / LPR;   // nodes per wave
    int wid = (blockIdx.x * blockDim.x + threadIdx.x) >> 6;
    int lane = threadIdx.x & 63;
    int sub = lane & (LPR - 1);
    int g = lane / LPR;
    int node = wid * NPW + g;
    bool vn = node < N;
    int nc = vn ? node : N - 1;
    int s = rowptr[nc];
    int e = vn ? rowptr[nc + 1] : s;
    const unsigned char* To = T8 + sub * 16;
    floatx2 a[8];
#pragma unroll
    for (int i = 0; i < 8; i++) a[i] = (floatx2){0.f, 0.f};
    for (int j = s; j < e; j += 4) {
        int j1 = (j + 1 < e) ? j + 1 : j;
        int j2 = (j + 2 < e) ? j + 2 : j;
        int j3 = (j + 3 < e) ? j + 3 : j;
        float m1 = (j + 1 < e) ? 1.f : 0.f;
        float m2 = (j + 2 < e) ? 1.f : 0.f;
        float m3 = (j + 3 < e) ? 1.f : 0.f;
        int c0 = col[j], c1 = col[j1], c2 = col[j2], c3 = col[j3];
        uint4 v0 = *(const uint4*)(To + (size_t)c0 * RSB);
        uint4 v1 = *(const uint4*)(To + (size_t)c1 * RSB);
        uint4 v2 = *(const uint4*)(To + (size_t)c2 * RSB);
        uint4 v3 = *(const uint4*)(To + (size_t)c3 * RSB);
        acc16_fp8(v0, 1.f, a);
        acc16_fp8(v1, m1, a);
        acc16_fp8(v2, m2, a);
        acc16_fp8(v3, m3, a);
    }
    if (vn) {
        float inv = invdeg[node];
        uint4 o1, o2;
        o1.x = (unsigned)f2bf(a[0].x * inv) | ((unsigned)f2bf(a[0].y * inv) << 16);
        o1.y = (unsigned)f2bf(a[1].x * inv) | ((unsigned)f2bf(a[1].y * inv) << 16);
        o1.z = (unsigned)f2bf(a[2].x * inv) | ((unsigned)f2bf(a[2].y * inv) << 16);
        o1.w = (unsigned)f2bf(a[3].x * inv) | ((unsigned)f2bf(a[3].y * inv) << 16);
        o2.x = (unsigned)f2bf(a[4].x * inv) | ((unsigned)f2bf(a[4].y * inv) << 16);
        o2.y = (unsigned)f2bf(a[5].x * inv) | ((unsigned)f2bf(a[5].y * inv) << 16);
        o2.z = (unsigned)f2bf(a[6].x * inv) | ((unsigned)f2bf(a[6].y * inv) << 16);
        o2.w = (unsigned)f2bf(a[7].x * inv) | ((unsigned)f2bf(a[7].y * inv) << 16);
        unsigned short* op = out + (size_t)node * ostride + sub * 16;
        *(uint4*)op = o1;
        *(uint4*)(op + 8) = o2;
    }
}

// final gather-mean over bf16 table [N,128] (256B rows) + fp32 residual add.
// 16 lanes/row (8 bf16 per lane), 4 nodes/wave; fp32 out.
__global__ __launch_bounds__(256) void agg_fin_g(const int* __restrict__ rowptr,
                                                 const int* __restrict__ col,
                                                 const float* __restrict__ invdeg,
                                                 const unsigned short* __restrict__ T,
                                                 const float* __restrict__ R,
                                                 float* __restrict__ out, int N) {
    int wid = (blockIdx.x * blockDim.x + threadIdx.x) >> 6;
    int lane = threadIdx.x & 63;
    int sub = lane & 15;
    int g = lane >> 4;
    int node = wid * 4 + g;
    bool vn = node < N;
    int nc = vn ? node : N - 1;
    int s = rowptr[nc];
    int e = vn ? rowptr[nc + 1] : s;
    const unsigned short* To = T + sub * 8;
    floatx2 a[4];
#pragma unroll
    for (int i = 0; i < 4; i++) a[i] = (floatx2){0.f, 0.f};
    for (int j = s; j < e; j += 4) {
        int j1 = (j + 1 < e) ? j + 1 : j;
        int j2 = (j + 2 < e) ? j + 2 : j;
        int j3 = (j + 3 < e) ? j + 3 : j;
        float m1 = (j + 1 < e) ? 1.f : 0.f;
        float m2 = (j + 2 < e) ? 1.f : 0.f;
        float m3 = (j + 3 < e) ? 1.f : 0.f;
        int c0 = col[j], c1 = col[j1], c2 = col[j2], c3 = col[j3];
        uint4 v0 = *(const uint4*)(To + (size_t)c0 * 128);
        uint4 v1 = *(const uint4*)(To + (size_t)c1 * 128);
        uint4 v2 = *(const uint4*)(To + (size_t)c2 * 128);
        uint4 v3 = *(const uint4*)(To + (size_t)c3 * 128);
        floatx2 mm;
        floatx2 p;
        mm = (floatx2){1.f, 1.f};
        p = (floatx2){bf2f_lo(v0.x), bf2f_hi(v0.x)}; a[0] = p + a[0];
        p = (floatx2){bf2f_lo(v0.y), bf2f_hi(v0.y)}; a[1] = p + a[1];
        p = (floatx2){bf2f_lo(v0.z), bf2f_hi(v0.z)}; a[2] = p + a[2];
        p = (floatx2){bf2f_lo(v0.w), bf2f_hi(v0.w)}; a[3] = p + a[3];
        mm = (floatx2){m1, m1};
        p = (floatx2){bf2f_lo(v1.x), bf2f_hi(v1.x)}; a[0] = p * mm + a[0];
        p = (floatx2){bf2f_lo(v1.y), bf2f_hi(v1.y)}; a[1] = p * mm + a[1];
        p = (floatx2){bf2f_lo(v1.z), bf2f_hi(v1.z)}; a[2] = p * mm + a[2];
        p = (floatx2){bf2f_lo(v1.w), bf2f_hi(v1.w)}; a[3] = p * mm + a[3];
        mm = (floatx2){m2, m2};
        p = (floatx2){bf2f_lo(v2.x), bf2f_hi(v2.x)}; a[0] = p * mm + a[0];
        p = (floatx2){bf2f_lo(v2.y), bf2f_hi(v2.y)}; a[1] = p * mm + a[1];
        p = (floatx2){bf2f_lo(v2.z), bf2f_hi(v2.z)}; a[2] = p * mm + a[2];
        p = (floatx2){bf2f_lo(v2.w), bf2f_hi(v2.w)}; a[3] = p * mm + a[3];
        mm = (floatx2){m3, m3};
        p = (floatx2){bf2f_lo(v3.x), bf2f_hi(v3.x)}; a[0] = p * mm + a[0];
        p = (floatx2){bf2f_lo(v3.y), bf2f_hi(v3.y)}; a[1] = p * mm + a[1];
        p = (floatx2){bf2f_lo(v3.z), bf2f_hi(v3.z)}; a[2] = p * mm + a[2];
        p = (floatx2){bf2f_lo(v3.w), bf2f_hi(v3.w)}; a[3] = p * mm + a[3];
    }
    if (vn) {
        float inv = invdeg[node];
        const float* Rp = R + (size_t)node * 128 + sub * 8;
        float4 r1 = *(const float4*)Rp;
        float4 r2 = *(const float4*)(Rp + 4);
        float4 o1, o2;
        o1.x = a[0].x * inv + r1.x; o1.y = a[0].y * inv + r1.y;
        o1.z = a[1].x * inv + r1.z; o1.w = a[1].y * inv + r1.w;
        o2.x = a[2].x * inv + r2.x; o2.y = a[2].y * inv + r2.y;
        o2.z = a[3].x * inv + r2.z; o2.w = a[3].y * inv + r2.w;
        float* op = out + (size_t)node * 128 + sub * 8;
        *(float4*)op = o1;
        *(float4*)(op + 4) = o2;
    }
}

// ====== GEMM (round-3 structure): A via LDS dbuf, B direct global->VGPR (L2-resident
// weights), fused LN/ReLU/residual epilogue through an LDS row-exchange buffer. ======
// 512 threads = 8 waves; block computes 128 rows x COLS (COLS = NPAN*256).
// MODE 0 (layer1): COLS=512 = [u|s]; h = relu(LN(u+b1l)*g+b) + (s+bsk) -> bf16 + fp8.
// MODE 1 (layer2): COLS=256; h2 = relu(LN(u2+b2l)*g+b) + resid(bf16 stride 512) -> bf16.
// MODE 2 (layer3): COLS=256; cols 0-127 -> t3 bf16 (no bias); cols 128-255 + bias -> r3 fp32.
template <int KIT, int NPAN, int MODE>
__global__ __launch_bounds__(512) void gemm_fused(
    const unsigned short* __restrict__ A, int lda,
    const unsigned short* __restrict__ B, int ldb,
    const float* __restrict__ bias,
    const float* __restrict__ gamma, const float* __restrict__ beta,
    const unsigned short* __restrict__ resid,
    unsigned short* __restrict__ outb,
    unsigned char* __restrict__ h8,
    float* __restrict__ outf, int M) {
    constexpr int COLS = NPAN * 256;
    constexpr int LNW = COLS + 8;              // exchange-buffer row stride (floats)
    constexpr int STAGE_E = 128 * 64;          // A-tile bf16 elems (16 KB)
    constexpr int STAGE_F = 2 * STAGE_E / 2;   // dbuf bytes/4 = floats (8192)
    constexpr int SMEM_F = (STAGE_F > 32 * LNW) ? STAGE_F : 32 * LNW;
    __shared__ __align__(16) float smemf[SMEM_F];
    unsigned short* sbase = (unsigned short*)smemf;

    int t = threadIdx.x;
    int lane = t & 63, w = t >> 6;
    int bm = blockIdx.x * 128;
    int wm = (w & 1) * 64, wn = (w >> 1) * 64;
    int m16 = lane & 15, kq = lane >> 4;

    floatx4 acc[NPAN][4][4];
#pragma unroll
    for (int p = 0; p < NPAN; p++)
#pragma unroll
        for (int i = 0; i < 4; i++)
#pragma unroll
            for (int j = 0; j < 4; j++) acc[p][i][j] = (floatx4){0.f, 0.f, 0.f, 0.f};

    const int s_row0 = t >> 3;                 // staging rows 0..63 (i=0), +64 (i=1)
    const int s_j = t & 7;

    auto stage = [&](int kt, int bsel) {
        unsigned short* s = sbase + bsel * STAGE_E;
        int k0 = kt * 64;
#pragma unroll
        for (int i = 0; i < 2; i++) {
            int row = s_row0 + i * 64;
            int kc = s_j ^ (row & 7);          // XOR-swizzled source k-chunk
            int rowA = bm + row;
            if (rowA > M - 1) rowA = M - 1;
            gl_lds16(A + (size_t)rowA * lda + k0 + kc * 8, (void*)&s[(size_t)(i * 512 + t) * 8]);
        }
    };

    stage(0, 0);
    __syncthreads();
    for (int kt = 0; kt < KIT; kt++) {
        if (kt + 1 < KIT) stage(kt + 1, (kt & 1) ^ 1);
        const unsigned short* sA = sbase + (kt & 1) * STAGE_E;
#pragma unroll
        for (int ks = 0; ks < 2; ks++) {
            int kcl = (ks << 2) | kq;
            bf16x8 af[4];
#pragma unroll
            for (int mi = 0; mi < 4; mi++)
                af[mi] = *(const bf16x8*)&sA[(wm + mi * 16 + m16) * 64 + (kcl ^ (m16 & 7)) * 8];
#pragma unroll
            for (int p = 0; p < NPAN; p++) {
                if (MODE == 0 && p == 1 && kt * 64 < 128) continue;  // Wsk panel: k<128 is zero
                const unsigned short* Bp = B + (size_t)(wn + p * 256) * ldb + kt * 64;
                bf16x8 bf[4];
#pragma unroll
                for (int ni = 0; ni < 4; ni++)
                    bf[ni] = *(const bf16x8*)&Bp[(size_t)(ni * 16 + m16) * ldb + kcl * 8];
#pragma unroll
                for (int mi = 0; mi < 4; mi++)
#pragma unroll
                    for (int ni = 0; ni < 4; ni++)
                        acc[p][mi][ni] =
                            __builtin_amdgcn_mfma_f32_16x16x32_bf16(af[mi], bf[ni], acc[p][mi][ni], 0, 0, 0);
            }
        }
        __syncthreads();
    }

    // ---- fused epilogue: 4 rounds of 32 rows through LDS exchange buffer ----
    float* lnb = smemf;
    int c4 = lane * 4;
    float4 bu = {0.f, 0.f, 0.f, 0.f}, bs = {0.f, 0.f, 0.f, 0.f};
    float4 gv = {0.f, 0.f, 0.f, 0.f}, bv = {0.f, 0.f, 0.f, 0.f};
    float4 b3 = {0.f, 0.f, 0.f, 0.f};
    if (MODE == 0) {
        bu = *(const float4*)&bias[c4];
        bs = *(const float4*)&bias[256 + c4];
        gv = *(const float4*)&gamma[c4];
        bv = *(const float4*)&beta[c4];
    } else if (MODE == 1) {
        bu = *(const float4*)&bias[c4];
        gv = *(const float4*)&gamma[c4];
        bv = *(const float4*)&beta[c4];
    } else {
        if (lane >= 32) b3 = *(const float4*)&bias[c4 - 128];
    }

#pragma unroll
    for (int g4 = 0; g4 < 4; g4++) {
        if (wm == (g4 >> 1) * 64) {            // this wave owns rows g4*32..+32
            int mi0 = (g4 & 1) * 2;
#pragma unroll
            for (int p = 0; p < NPAN; p++)
#pragma unroll
                for (int mm = 0; mm < 2; mm++)
#pragma unroll
                    for (int ni = 0; ni < 4; ni++)
#pragma unroll
                        for (int r = 0; r < 4; r++)
                            lnb[(mm * 16 + kq * 4 + r) * LNW + wn + p * 256 + ni * 16 + m16] =
                                acc[p][mi0 + mm][ni][r];
        }
        __syncthreads();
#pragma unroll
        for (int rr = 0; rr < 4; rr++) {
            int lrow = w * 4 + rr;             // 8 waves x 4 rows = 32
            int grow = bm + g4 * 32 + lrow;
            bool valid = grow < M;
            float4 u = *(const float4*)&lnb[lrow * LNW + c4];
            if (MODE <= 1) {
                u.x += bu.x; u.y += bu.y; u.z += bu.z; u.w += bu.w;
                float s1 = (u.x + u.y) + (u.z + u.w);
                float s2 = (u.x * u.x + u.y * u.y) + (u.z * u.z + u.w * u.w);
#pragma unroll
                for (int off = 1; off < 64; off <<= 1) {
                    s1 += __shfl_xor(s1, off, 64);
                    s2 += __shfl_xor(s2, off, 64);
                }
                float mu = s1 * (1.f / 256.f);
                float var = s2 * (1.f / 256.f) - mu * mu;
                float rs = rsqrtf(var + 1e-5f);
                float a0, a1, a2, a3;
                if (MODE == 0) {
                    float4 sv = *(const float4*)&lnb[lrow * LNW + 256 + c4];
                    a0 = sv.x + bs.x; a1 = sv.y + bs.y; a2 = sv.z + bs.z; a3 = sv.w + bs.w;
                } else {
                    int gr = valid ? grow : M - 1;
                    uint2 hv = *(const uint2*)(resid + (size_t)gr * 512 + c4);
                    a0 = bf2f_lo(hv.x); a1 = bf2f_hi(hv.x); a2 = bf2f_lo(hv.y); a3 = bf2f_hi(hv.y);
                }
                float o0 = fmaxf((u.x - mu) * rs * gv.x + bv.x, 0.f) + a0;
                float o1 = fmaxf((u.y - mu) * rs * gv.y + bv.y, 0.f) + a1;
                float o2 = fmaxf((u.z - mu) * rs * gv.z + bv.z, 0.f) + a2;
                float o3 = fmaxf((u.w - mu) * rs * gv.w + bv.w, 0.f) + a3;
                if (valid) {
                    ushort4 o;
                    o.x = f2bf(o0); o.y = f2bf(o1); o.z = f2bf(o2); o.w = f2bf(o3);
                    *(ushort4*)(outb + (size_t)grow * 512 + c4) = o;
                    if (MODE == 0) {
                        unsigned wpk = 0;
                        wpk = __builtin_amdgcn_cvt_pk_fp8_f32(o0, o1, wpk, false);
                        wpk = __builtin_amdgcn_cvt_pk_fp8_f32(o2, o3, wpk, true);
                        *(unsigned*)(h8 + (size_t)grow * 256 + c4) = wpk;
                    }
                }
            } else {
                if (valid) {
                    if (lane < 32) {
                        ushort4 o;
                        o.x = f2bf(u.x); o.y = f2bf(u.y); o.z = f2bf(u.z); o.w = f2bf(u.w);
                        *(ushort4*)(outb + (size_t)grow * 128 + c4) = o;
                    } else {
                        float4 o;
                        o.x = u.x + b3.x; o.y = u.y + b3.y; o.z = u.z + b3.z; o.w = u.w + b3.w;
                        *(float4*)(outf + (size_t)grow * 128 + (c4 - 128)) = o;
                    }
                }
            }
        }
        __syncthreads();
    }
}

// ================= launch =================
extern "C" void kernel_launch(void* const* d_in, const int* in_sizes, int n_in,
                              void* d_out, int out_size, void* d_ws, size_t ws_size,
                              hipStream_t stream) {
    const float* x   = (const float*)d_in[0];
    const int*   ei  = (const int*)d_in[1];
    const float* W1l = (const float*)d_in[2];
    const float* b1l = (const float*)d_in[3];
    const float* W1r = (const float*)d_in[4];
    const float* g1  = (const float*)d_in[5];
    const float* be1 = (const float*)d_in[6];
    const float* Wsk = (const float*)d_in[7];
    const float* bsk = (const float*)d_in[8];
    const float* W2l = (const float*)d_in[9];
    const float* b2l = (const float*)d_in[10];
    const float* W2r = (const float*)d_in[11];
    const float* g2  = (const float*)d_in[12];
    const float* be2 = (const float*)d_in[13];
    const float* W3l = (const float*)d_in[14];
    const float* b3l = (const float*)d_in[15];
    const float* W3r = (const float*)d_in[16];

    const int N = in_sizes[0] / 128;
    const int E = in_sizes[1] / 2;
    const int* src = ei;
    const int* dst = ei + E;

    char* p = (char*)d_ws;
    auto alloc = [&](size_t bytes) {
        void* r = (void*)p;
        p += (bytes + 255) & ~(size_t)255;
        return r;
    };
    int*   cnt    = (int*)alloc(sizeof(int) * N);
    int*   rowptr = (int*)alloc(sizeof(int) * (N + 1));
    int*   cursor = (int*)alloc(sizeof(int) * N);
    float* invdeg = (float*)alloc(sizeof(float) * N);
    int*   col    = (int*)alloc(sizeof(int) * E);
    int*   bsum   = (int*)alloc(sizeof(int) * 256);
    int*   boff   = (int*)alloc(sizeof(int) * 256);
    unsigned short* A1cat = (unsigned short*)alloc(sizeof(short) * (size_t)N * 256);  // [agg1|x]; later t3
    unsigned short* A2cat = (unsigned short*)alloc(sizeof(short) * (size_t)N * 512);  // [agg2|h] -> [h2|h]
    float* r3 = (float*)alloc(sizeof(float) * (size_t)N * 128);
    unsigned char* H8 = (unsigned char*)alloc((size_t)N * 256);                       // fp8 h shadow
    unsigned char* X8 = (unsigned char*)alloc((size_t)N * 128);                       // fp8 x shadow
    unsigned short* WtC = (unsigned short*)alloc(sizeof(short) * 512 * 256);
    unsigned short* Wt2 = (unsigned short*)alloc(sizeof(short) * 256 * 512);
    unsigned short* Wt3 = (unsigned short*)alloc(sizeof(short) * 256 * 256);
    float* biasC = (float*)alloc(sizeof(float) * 512);
    unsigned short* t3 = A1cat;

    // ---- CSR build ----
    hipMemsetAsync(cnt, 0, sizeof(int) * N, stream);
    hist_kernel<<<(E + 255) / 256, 256, 0, stream>>>(dst, cnt, E);
    int NB = (N + SCAN_CHUNK - 1) / SCAN_CHUNK;
    scan_blocksums<<<NB, 256, 0, stream>>>(cnt, bsum, N);
    scan_bsums<<<1, 256, 0, stream>>>(bsum, boff, NB, rowptr, N, E);
    scan_final<<<NB, 256, 0, stream>>>(cnt, boff, rowptr, cursor, invdeg, N);
    scatter_kernel<<<(E + 255) / 256, 256, 0, stream>>>(src, dst, cursor, col, E);

    // ---- prep ----
    prep_weights<<<(328192 + 255) / 256, 256, 0, stream>>>(W1l, W1r, Wsk, W2l, W2r, W3l, W3r,
                                                           b1l, bsk, WtC, Wt2, Wt3, biasC);
    cvt_x2<<<((N * 32) + 255) / 256, 256, 0, stream>>>(x, A1cat, X8, N * 32);

    int mBlocks = (N + 127) / 128;
    int agg1Blocks = (N + 31) / 32;    // 8 nodes/wave x 4 waves
    int agg2Blocks = (N + 15) / 16;    // 4 nodes/wave x 4 waves
    int aggFBlocks = (N + 15) / 16;

    // ---- layer 1: group agg -> fused GEMM+LN+ReLU+skip -> h (bf16 + fp8) ----
    agg_fp8_g<128><<<agg1Blocks, 256, 0, stream>>>(rowptr, col, invdeg, X8, A1cat, 256, N);
    gemm_fused<4, 2, 0><<<mBlocks, 512, 0, stream>>>(A1cat, 256, WtC, 256, biasC, g1, be1,
                                                     nullptr, A2cat + 256, H8, nullptr, N);

    // ---- layer 2: group agg -> fused GEMM+LN+ReLU+residual -> h2 ----
    agg_fp8_g<256><<<agg2Blocks, 256, 0, stream>>>(rowptr, col, invdeg, H8, A2cat, 512, N);
    gemm_fused<8, 1, 1><<<mBlocks, 512, 0, stream>>>(A2cat, 512, Wt2, 512, b2l, g2, be2,
                                                     A2cat + 256, A2cat, nullptr, nullptr, N);

    // ---- layer 3: split GEMM (t3 bf16 | r3 fp32+bias) -> group final agg ----
    gemm_fused<4, 1, 2><<<mBlocks, 512, 0, stream>>>(A2cat, 512, Wt3, 256, b3l, nullptr, nullptr,
                                                     nullptr, t3, nullptr, r3, N);
    agg_fin_g<<<aggFBlocks, 256, 0, stream>>>(rowptr, col, invdeg, t3, r3, (float*)d_out, N);
}